// Round 1
// baseline (9737.373 us; speedup 1.0000x reference)
//
#include <hip/hip_runtime.h>
#include <math.h>

#define NN 100000
#define NE 1600000

__global__ __launch_bounds__(256) void deg_init_k(int* degi, int n) {
    int i = blockIdx.x * 256 + threadIdx.x;
    if (i < n) degi[i] = 1;
}

__global__ __launch_bounds__(256) void deg_count_k(const int* __restrict__ dst, int* degi, int e) {
    int i = blockIdx.x * 256 + threadIdx.x;
    if (i < e) atomicAdd(&degi[dst[i]], 1);
}

__global__ __launch_bounds__(256) void dinv_k(const int* __restrict__ degi, float* __restrict__ dinv, int n) {
    int i = blockIdx.x * 256 + threadIdx.x;
    if (i < n) dinv[i] = 1.0f / sqrtf((float)degi[i]);
}

// C[n x HOUT] = act(A)[n x 128] @ W[128 x HOUT]
template<int HOUT, bool RELU>
__global__ __launch_bounds__(256) void gemm_k(const float* __restrict__ A,
                                              const float* __restrict__ W,
                                              float* __restrict__ C, int n) {
    constexpr int K  = 128;
    constexpr int BM = 64;
    constexpr int BK = 32;
    constexpr int CPT = HOUT / 16;   // cols per thread (8 for H=128, 4 for H=64)
    __shared__ float As[BK][BM + 4]; // +4 keeps float4 alignment, breaks some conflicts
    __shared__ float Ws[BK][HOUT];

    const int tid = threadIdx.x;
    const int tc = tid & 15;         // 16 col-groups
    const int tr = tid >> 4;         // 16 row-groups of 4 rows
    const int row0 = blockIdx.x * BM;

    float acc[4][CPT];
#pragma unroll
    for (int i = 0; i < 4; ++i)
#pragma unroll
        for (int j = 0; j < CPT; ++j) acc[i][j] = 0.f;

    for (int kb = 0; kb < K; kb += BK) {
        // ---- stage A tile (64 rows x 32 k), transposed into As[k][row]
#pragma unroll
        for (int it = 0; it < 2; ++it) {
            int idx = tid + it * 256;          // 0..511 float4s
            int r = idx >> 3, c4 = idx & 7;
            float4 v = make_float4(0.f, 0.f, 0.f, 0.f);
            if (row0 + r < n)
                v = *(const float4*)(A + (size_t)(row0 + r) * K + kb + c4 * 4);
            if (RELU) {
                v.x = fmaxf(v.x, 0.f); v.y = fmaxf(v.y, 0.f);
                v.z = fmaxf(v.z, 0.f); v.w = fmaxf(v.w, 0.f);
            }
            As[c4 * 4 + 0][r] = v.x;
            As[c4 * 4 + 1][r] = v.y;
            As[c4 * 4 + 2][r] = v.z;
            As[c4 * 4 + 3][r] = v.w;
        }
        // ---- stage W tile (32 x HOUT)
        constexpr int WF4 = BK * HOUT / 4;
#pragma unroll
        for (int it = 0; it < WF4 / 256; ++it) {
            int idx = tid + it * 256;
            int r = idx / (HOUT / 4), c4 = idx % (HOUT / 4);
            *(float4*)&Ws[r][c4 * 4] = *(const float4*)(W + (size_t)(kb + r) * HOUT + c4 * 4);
        }
        __syncthreads();

#pragma unroll
        for (int k = 0; k < BK; ++k) {
            float4 a4 = *(const float4*)&As[k][tr * 4];
            float a[4] = {a4.x, a4.y, a4.z, a4.w};
            float w[CPT];
#pragma unroll
            for (int j4 = 0; j4 < CPT / 4; ++j4) {
                float4 w4 = *(const float4*)&Ws[k][tc * CPT + j4 * 4];
                w[j4 * 4 + 0] = w4.x; w[j4 * 4 + 1] = w4.y;
                w[j4 * 4 + 2] = w4.z; w[j4 * 4 + 3] = w4.w;
            }
#pragma unroll
            for (int i = 0; i < 4; ++i)
#pragma unroll
                for (int j = 0; j < CPT; ++j)
                    acc[i][j] = fmaf(a[i], w[j], acc[i][j]);
        }
        __syncthreads();
    }

#pragma unroll
    for (int i = 0; i < 4; ++i) {
        int row = row0 + tr * 4 + i;
        if (row < n) {
#pragma unroll
            for (int j4 = 0; j4 < CPT / 4; ++j4) {
                float4 v = make_float4(acc[i][j4 * 4 + 0], acc[i][j4 * 4 + 1],
                                       acc[i][j4 * 4 + 2], acc[i][j4 * 4 + 3]);
                *(float4*)(C + (size_t)row * HOUT + tc * CPT + j4 * 4) = v;
            }
        }
    }
}

// out[i][:] = tmp[i][:] * dinv[i]^2 + b   (self-loop + bias, full overwrite)
template<int HOUT>
__global__ __launch_bounds__(256) void init_out_k(const float* __restrict__ tmp,
                                                  const float* __restrict__ dinv,
                                                  const float* __restrict__ b,
                                                  float* __restrict__ out, int n) {
    constexpr int F4 = HOUT / 4;
    int gid = blockIdx.x * 256 + threadIdx.x;
    int i = gid / F4, c4 = gid % F4;
    if (i >= n) return;
    float s = dinv[i]; s *= s;
    float4 v = *(const float4*)(tmp + (size_t)i * HOUT + c4 * 4);
    float4 bb = *(const float4*)(b + c4 * 4);
    float4 o;
    o.x = fmaf(v.x, s, bb.x); o.y = fmaf(v.y, s, bb.y);
    o.z = fmaf(v.z, s, bb.z); o.w = fmaf(v.w, s, bb.w);
    *(float4*)(out + (size_t)i * HOUT + c4 * 4) = o;
}

// out[dst][:] += tmp[src][:] * dinv[src]*dinv[dst]  per edge, atomics
template<int HOUT>
__global__ __launch_bounds__(256) void scatter_k(const float* __restrict__ tmp,
                                                 const int* __restrict__ src,
                                                 const int* __restrict__ dst,
                                                 const float* __restrict__ dinv,
                                                 float* out, int e) {
    constexpr int L = HOUT / 4;  // lanes per edge
    int gid = blockIdx.x * 256 + threadIdx.x;
    int ed = gid / L, l = gid % L;
    if (ed >= e) return;
    int s = src[ed], d = dst[ed];
    float c = dinv[s] * dinv[d];
    float4 v = *(const float4*)(tmp + (size_t)s * HOUT + l * 4);
    float* o = out + (size_t)d * HOUT + l * 4;
    atomicAdd(o + 0, v.x * c);
    atomicAdd(o + 1, v.y * c);
    atomicAdd(o + 2, v.z * c);
    atomicAdd(o + 3, v.w * c);
}

extern "C" void kernel_launch(void* const* d_in, const int* in_sizes, int n_in,
                              void* d_out, int out_size, void* d_ws, size_t ws_size,
                              hipStream_t stream) {
    const float* x   = (const float*)d_in[0];
    const int*   ei  = (const int*)d_in[1];
    const int*   srcp = ei;
    const int*   dstp = ei + NE;
    const float* W0 = (const float*)d_in[2]; const float* b0 = (const float*)d_in[3];
    const float* W1 = (const float*)d_in[4]; const float* b1 = (const float*)d_in[5];
    const float* W2 = (const float*)d_in[6]; const float* b2 = (const float*)d_in[7];
    const float* W3 = (const float*)d_in[8]; const float* b3 = (const float*)d_in[9];
    float* out = (float*)d_out;

    char* ws = (char*)d_ws;
    int*   degi = (int*)ws;                                   // N ints
    float* dinv = (float*)(ws + (size_t)NN * 4);              // N floats
    float* bufA = (float*)(ws + (size_t)NN * 8);              // N*128 floats (gemm out)
    float* bufB = bufA + (size_t)NN * 128;                    // N*128 floats (conv out)

    const int nblk_n  = (NN + 255) / 256;
    const int nblk_e  = (NE + 255) / 256;
    const int nblk_g  = (NN + 63) / 64;
    const int nblk_i128 = (NN * 32 + 255) / 256;
    const int nblk_i64  = (NN * 16 + 255) / 256;
    const int nblk_s128 = (int)(((size_t)NE * 32 + 255) / 256);
    const int nblk_s64  = (int)(((size_t)NE * 16 + 255) / 256);

    // degree (dst-indegree + 1 self loop), dinv = rsqrt(deg)
    deg_init_k<<<nblk_n, 256, 0, stream>>>(degi, NN);
    deg_count_k<<<nblk_e, 256, 0, stream>>>(dstp, degi, NE);
    dinv_k<<<nblk_n, 256, 0, stream>>>(degi, dinv, NN);

    // layer 0: x -> bufB
    gemm_k<128, false><<<nblk_g, 256, 0, stream>>>(x, W0, bufA, NN);
    init_out_k<128><<<nblk_i128, 256, 0, stream>>>(bufA, dinv, b0, bufB, NN);
    scatter_k<128><<<nblk_s128, 256, 0, stream>>>(bufA, srcp, dstp, dinv, bufB, NE);

    // layer 1: relu(bufB) -> bufB
    gemm_k<128, true><<<nblk_g, 256, 0, stream>>>(bufB, W1, bufA, NN);
    init_out_k<128><<<nblk_i128, 256, 0, stream>>>(bufA, dinv, b1, bufB, NN);
    scatter_k<128><<<nblk_s128, 256, 0, stream>>>(bufA, srcp, dstp, dinv, bufB, NE);

    // layer 2: relu(bufB) -> bufB
    gemm_k<128, true><<<nblk_g, 256, 0, stream>>>(bufB, W2, bufA, NN);
    init_out_k<128><<<nblk_i128, 256, 0, stream>>>(bufA, dinv, b2, bufB, NN);
    scatter_k<128><<<nblk_s128, 256, 0, stream>>>(bufA, srcp, dstp, dinv, bufB, NE);

    // layer 3: relu(bufB) -> d_out (no activation)
    gemm_k<64, true><<<nblk_g, 256, 0, stream>>>(bufB, W3, bufA, NN);
    init_out_k<64><<<nblk_i64, 256, 0, stream>>>(bufA, dinv, b3, out, NN);
    scatter_k<64><<<nblk_s64, 256, 0, stream>>>(bufA, srcp, dstp, dinv, out, NE);
}

// Round 2
// 892.111 us; speedup vs baseline: 10.9150x; 10.9150x over previous
//
#include <hip/hip_runtime.h>
#include <math.h>

#define NN 100000
#define NE 1600000

// ---------------- degree / dinv ----------------
__global__ __launch_bounds__(256) void deg_init_k(int* degi, int n) {
    int i = blockIdx.x * 256 + threadIdx.x;
    if (i < n) degi[i] = 1;   // self loop
}

__global__ __launch_bounds__(256) void deg_count_k(const int* __restrict__ dst, int* degi, int e) {
    int i = blockIdx.x * 256 + threadIdx.x;
    if (i < e) atomicAdd(&degi[dst[i]], 1);
}

__global__ __launch_bounds__(256) void dinv_k(const int* __restrict__ degi, float* __restrict__ dinv, int n) {
    int i = blockIdx.x * 256 + threadIdx.x;
    if (i < n) dinv[i] = 1.0f / sqrtf((float)degi[i]);
}

// ---------------- exclusive scan of in-degree (deterministic, single WG) ----------------
__global__ __launch_bounds__(1024) void scan_k(const int* __restrict__ degi,
                                               int* __restrict__ rowptr,
                                               int* __restrict__ cursor, int n) {
    __shared__ int wsum[16];
    __shared__ int carry_s;
    const int tid = threadIdx.x;
    const int lane = tid & 63, wid = tid >> 6;
    if (tid == 0) carry_s = 0;
    __syncthreads();
    for (int base = 0; base < n; base += 1024) {
        int i = base + tid;
        int deg_in = (i < n) ? (degi[i] - 1) : 0;  // in-degree excl self loop
        int v = deg_in;
        // wave inclusive scan
        #pragma unroll
        for (int off = 1; off < 64; off <<= 1) {
            int t = __shfl_up(v, off);
            if (lane >= off) v += t;
        }
        if (lane == 63) wsum[wid] = v;
        __syncthreads();
        if (wid == 0 && lane < 16) {
            int w = wsum[lane];
            #pragma unroll
            for (int off = 1; off < 16; off <<= 1) {
                int t = __shfl_up(w, off);
                if (lane >= off) w += t;
            }
            wsum[lane] = w;  // inclusive wave-sum scan
        }
        __syncthreads();
        int waveoff = (wid == 0) ? 0 : wsum[wid - 1];
        int carry = carry_s;
        int excl = (v - deg_in) + waveoff + carry;
        if (i < n) { rowptr[i] = excl; cursor[i] = excl; }
        __syncthreads();                 // everyone read carry_s
        if (tid == 1023) carry_s = carry + wsum[15];
        __syncthreads();
    }
    if (tid == 0) rowptr[n] = carry_s;
}

// ---------------- CSR fill ----------------
__global__ __launch_bounds__(256) void fill_k(const int* __restrict__ src,
                                              const int* __restrict__ dst,
                                              int* cursor, int* __restrict__ csr_src, int e) {
    int i = blockIdx.x * 256 + threadIdx.x;
    if (i < e) {
        int d = dst[i];
        int pos = atomicAdd(&cursor[d], 1);
        csr_src[pos] = src[i];
    }
}

// ---------------- GEMM: C[n x HOUT] = act(A)[n x 128] @ W[128 x HOUT] ----------------
template<int HOUT, bool RELU>
__global__ __launch_bounds__(256) void gemm_k(const float* __restrict__ A,
                                              const float* __restrict__ W,
                                              float* __restrict__ C, int n) {
    constexpr int K  = 128;
    constexpr int BM = 64;
    constexpr int BK = 32;
    constexpr int CPT = HOUT / 16;
    __shared__ float As[BK][BM + 4];
    __shared__ float Ws[BK][HOUT];

    const int tid = threadIdx.x;
    const int tc = tid & 15;
    const int tr = tid >> 4;
    const int row0 = blockIdx.x * BM;

    float acc[4][CPT];
#pragma unroll
    for (int i = 0; i < 4; ++i)
#pragma unroll
        for (int j = 0; j < CPT; ++j) acc[i][j] = 0.f;

    for (int kb = 0; kb < K; kb += BK) {
#pragma unroll
        for (int it = 0; it < 2; ++it) {
            int idx = tid + it * 256;
            int r = idx >> 3, c4 = idx & 7;
            float4 v = make_float4(0.f, 0.f, 0.f, 0.f);
            if (row0 + r < n)
                v = *(const float4*)(A + (size_t)(row0 + r) * K + kb + c4 * 4);
            if (RELU) {
                v.x = fmaxf(v.x, 0.f); v.y = fmaxf(v.y, 0.f);
                v.z = fmaxf(v.z, 0.f); v.w = fmaxf(v.w, 0.f);
            }
            As[c4 * 4 + 0][r] = v.x;
            As[c4 * 4 + 1][r] = v.y;
            As[c4 * 4 + 2][r] = v.z;
            As[c4 * 4 + 3][r] = v.w;
        }
        constexpr int WF4 = BK * HOUT / 4;
#pragma unroll
        for (int it = 0; it < WF4 / 256; ++it) {
            int idx = tid + it * 256;
            int r = idx / (HOUT / 4), c4 = idx % (HOUT / 4);
            *(float4*)&Ws[r][c4 * 4] = *(const float4*)(W + (size_t)(kb + r) * HOUT + c4 * 4);
        }
        __syncthreads();

#pragma unroll
        for (int k = 0; k < BK; ++k) {
            float4 a4 = *(const float4*)&As[k][tr * 4];
            float a[4] = {a4.x, a4.y, a4.z, a4.w};
            float w[CPT];
#pragma unroll
            for (int j4 = 0; j4 < CPT / 4; ++j4) {
                float4 w4 = *(const float4*)&Ws[k][tc * CPT + j4 * 4];
                w[j4 * 4 + 0] = w4.x; w[j4 * 4 + 1] = w4.y;
                w[j4 * 4 + 2] = w4.z; w[j4 * 4 + 3] = w4.w;
            }
#pragma unroll
            for (int i = 0; i < 4; ++i)
#pragma unroll
                for (int j = 0; j < CPT; ++j)
                    acc[i][j] = fmaf(a[i], w[j], acc[i][j]);
        }
        __syncthreads();
    }

#pragma unroll
    for (int i = 0; i < 4; ++i) {
        int row = row0 + tr * 4 + i;
        if (row < n) {
#pragma unroll
            for (int j4 = 0; j4 < CPT / 4; ++j4) {
                float4 v = make_float4(acc[i][j4 * 4 + 0], acc[i][j4 * 4 + 1],
                                       acc[i][j4 * 4 + 2], acc[i][j4 * 4 + 3]);
                *(float4*)(C + (size_t)row * HOUT + tc * CPT + j4 * 4) = v;
            }
        }
    }
}

// ---------------- gather-aggregate (atomic-free) ----------------
// out[d][:] = dinv[d] * ( tmp[d][:]*dinv[d] + sum_{s in in(d)} tmp[s][:]*dinv[s] ) + b
template<int HOUT>
__global__ __launch_bounds__(256) void agg_k(const float* __restrict__ tmp,
                                             const int* __restrict__ csr_src,
                                             const int* __restrict__ rowptr,
                                             const float* __restrict__ dinv,
                                             const float* __restrict__ b,
                                             float* __restrict__ out, int n) {
    constexpr int LPN = HOUT / 4;   // lanes per node
    int gid = blockIdx.x * 256 + threadIdx.x;
    int node = gid / LPN, l = gid % LPN;
    if (node >= n) return;

    const float dn = dinv[node];
    float4 bb = *(const float4*)(b + l * 4);
    float4 t = *(const float4*)(tmp + (size_t)node * HOUT + l * 4);
    float4 acc;
    acc.x = t.x * dn; acc.y = t.y * dn; acc.z = t.z * dn; acc.w = t.w * dn;

    int e = rowptr[node];
    const int end = rowptr[node + 1];
    int sidx = (e < end) ? csr_src[e] : 0;
    while (e < end) {
        int cur = sidx;
        ++e;
        if (e < end) sidx = csr_src[e];     // prefetch next edge
        float c = dinv[cur];
        float4 v = *(const float4*)(tmp + (size_t)cur * HOUT + l * 4);
        acc.x = fmaf(v.x, c, acc.x);
        acc.y = fmaf(v.y, c, acc.y);
        acc.z = fmaf(v.z, c, acc.z);
        acc.w = fmaf(v.w, c, acc.w);
    }
    float4 o;
    o.x = fmaf(acc.x, dn, bb.x);
    o.y = fmaf(acc.y, dn, bb.y);
    o.z = fmaf(acc.z, dn, bb.z);
    o.w = fmaf(acc.w, dn, bb.w);
    *(float4*)(out + (size_t)node * HOUT + l * 4) = o;
}

extern "C" void kernel_launch(void* const* d_in, const int* in_sizes, int n_in,
                              void* d_out, int out_size, void* d_ws, size_t ws_size,
                              hipStream_t stream) {
    const float* x    = (const float*)d_in[0];
    const int*   ei   = (const int*)d_in[1];
    const int*   srcp = ei;
    const int*   dstp = ei + NE;
    const float* W0 = (const float*)d_in[2]; const float* b0 = (const float*)d_in[3];
    const float* W1 = (const float*)d_in[4]; const float* b1 = (const float*)d_in[5];
    const float* W2 = (const float*)d_in[6]; const float* b2 = (const float*)d_in[7];
    const float* W3 = (const float*)d_in[8]; const float* b3 = (const float*)d_in[9];
    float* out = (float*)d_out;

    char* ws = (char*)d_ws;
    size_t off = 0;
    auto alloc = [&](size_t bytes) { void* p = ws + off; off = (off + bytes + 255) & ~(size_t)255; return p; };
    int*   degi    = (int*)alloc((size_t)NN * 4);
    float* dinv    = (float*)alloc((size_t)NN * 4);
    int*   rowptr  = (int*)alloc((size_t)(NN + 1) * 4);
    int*   cursor  = (int*)alloc((size_t)NN * 4);
    int*   csr_src = (int*)alloc((size_t)NE * 4);
    float* bufA    = (float*)alloc((size_t)NN * 128 * 4);
    float* bufB    = (float*)alloc((size_t)NN * 128 * 4);

    const int nblk_n = (NN + 255) / 256;
    const int nblk_e = (NE + 255) / 256;
    const int nblk_g = (NN + 63) / 64;
    const int nblk_a128 = (int)(((size_t)NN * 32 + 255) / 256);
    const int nblk_a64  = (int)(((size_t)NN * 16 + 255) / 256);

    // ---- graph preprocessing (per call, deterministic offsets) ----
    deg_init_k<<<nblk_n, 256, 0, stream>>>(degi, NN);
    deg_count_k<<<nblk_e, 256, 0, stream>>>(dstp, degi, NE);
    dinv_k<<<nblk_n, 256, 0, stream>>>(degi, dinv, NN);
    scan_k<<<1, 1024, 0, stream>>>(degi, rowptr, cursor, NN);
    fill_k<<<nblk_e, 256, 0, stream>>>(srcp, dstp, cursor, csr_src, NE);

    // ---- layer 0 ----
    gemm_k<128, false><<<nblk_g, 256, 0, stream>>>(x, W0, bufA, NN);
    agg_k<128><<<nblk_a128, 256, 0, stream>>>(bufA, csr_src, rowptr, dinv, b0, bufB, NN);
    // ---- layer 1 ----
    gemm_k<128, true><<<nblk_g, 256, 0, stream>>>(bufB, W1, bufA, NN);
    agg_k<128><<<nblk_a128, 256, 0, stream>>>(bufA, csr_src, rowptr, dinv, b1, bufB, NN);
    // ---- layer 2 ----
    gemm_k<128, true><<<nblk_g, 256, 0, stream>>>(bufB, W2, bufA, NN);
    agg_k<128><<<nblk_a128, 256, 0, stream>>>(bufA, csr_src, rowptr, dinv, b2, bufB, NN);
    // ---- layer 3 ----
    gemm_k<64, true><<<nblk_g, 256, 0, stream>>>(bufB, W3, bufA, NN);
    agg_k<64><<<nblk_a64, 256, 0, stream>>>(bufA, csr_src, rowptr, dinv, b3, out, NN);
}

// Round 3
// 860.333 us; speedup vs baseline: 11.3182x; 1.0369x over previous
//
#include <hip/hip_runtime.h>
#include <math.h>

#define NN 100000
#define NE 1600000

typedef __attribute__((ext_vector_type(8))) short short8;
typedef __attribute__((ext_vector_type(4))) float f32x4;

union frag8 { short s[8]; short8 v; };

// split fp32 into bf16 hi (truncated) + bf16 lo (rounded residual)
__device__ __forceinline__ void split_bf16(float a, short& hi, short& lo) {
    unsigned u = __float_as_uint(a);
    unsigned hb = u & 0xffff0000u;
    hi = (short)(hb >> 16);
    float r = a - __uint_as_float(hb);          // exact
    unsigned lu = __float_as_uint(r);
    lo = (short)((lu + 0x7fff + ((lu >> 16) & 1)) >> 16);  // RNE to bf16
}

// ---------------- degree / dinv ----------------
__global__ __launch_bounds__(256) void deg_init_k(int* degi, int n) {
    int i = blockIdx.x * 256 + threadIdx.x;
    if (i < n) degi[i] = 1;   // self loop
}

__global__ __launch_bounds__(256) void deg_count_k(const int* __restrict__ dst, int* degi, int e) {
    int i = blockIdx.x * 256 + threadIdx.x;
    if (i < e) atomicAdd(&degi[dst[i]], 1);
}

__global__ __launch_bounds__(256) void dinv_k(const int* __restrict__ degi, float* __restrict__ dinv, int n) {
    int i = blockIdx.x * 256 + threadIdx.x;
    if (i < n) dinv[i] = 1.0f / sqrtf((float)degi[i]);
}

// ---------------- parallel scan (3 kernels) ----------------
// block covers 4096 elements
__global__ __launch_bounds__(256) void bsum_k(const int* __restrict__ degi, int* __restrict__ bsum, int n) {
    __shared__ int wsum[4];
    int t = threadIdx.x;
    int base = blockIdx.x * 4096;
    int s = 0;
#pragma unroll
    for (int j = 0; j < 16; ++j) {
        int i = base + j * 256 + t;
        if (i < n) s += degi[i] - 1;    // in-degree excl self loop
    }
#pragma unroll
    for (int off = 32; off; off >>= 1) s += __shfl_down(s, off);
    if ((t & 63) == 0) wsum[t >> 6] = s;
    __syncthreads();
    if (t == 0) bsum[blockIdx.x] = wsum[0] + wsum[1] + wsum[2] + wsum[3];
}

__global__ __launch_bounds__(64) void bscan_k(const int* __restrict__ bsum, int* __restrict__ boff,
                                              int* __restrict__ rowptr_end, int nb) {
    int l = threadIdx.x;
    int v = (l < nb) ? bsum[l] : 0;
    int inc = v;
#pragma unroll
    for (int off = 1; off < 64; off <<= 1) {
        int t = __shfl_up(inc, off);
        if (l >= off) inc += t;
    }
    if (l < nb) boff[l] = inc - v;
    if (l == 63) *rowptr_end = inc;
}

__global__ __launch_bounds__(256) void scan2_k(const int* __restrict__ degi, const int* __restrict__ boff,
                                               int* __restrict__ rowptr, int* __restrict__ cursor, int n) {
    __shared__ int wsum[4];
    int t = threadIdx.x, lane = t & 63, wid = t >> 6;
    int base = blockIdx.x * 4096 + t * 16;
    int d[16];
    int s = 0;
#pragma unroll
    for (int j = 0; j < 16; ++j) {
        int i = base + j;
        d[j] = (i < n) ? (degi[i] - 1) : 0;
        s += d[j];
    }
    int inc = s;
#pragma unroll
    for (int off = 1; off < 64; off <<= 1) {
        int tt = __shfl_up(inc, off);
        if (lane >= off) inc += tt;
    }
    if (lane == 63) wsum[wid] = inc;
    __syncthreads();
    int woff = 0;
    for (int w = 0; w < wid; ++w) woff += wsum[w];
    int excl = inc - s + woff + boff[blockIdx.x];
#pragma unroll
    for (int j = 0; j < 16; ++j) {
        int i = base + j;
        if (i < n) { rowptr[i] = excl; cursor[i] = excl; }
        excl += d[j];
    }
}

// ---------------- CSR fill ----------------
__global__ __launch_bounds__(256) void fill_k(const int* __restrict__ src,
                                              const int* __restrict__ dst,
                                              int* cursor, int* __restrict__ csr_src, int e) {
    int i = blockIdx.x * 256 + threadIdx.x;
    if (i < e) {
        int d = dst[i];
        int pos = atomicAdd(&cursor[d], 1);
        csr_src[pos] = src[i];
    }
}

// ---------------- W pre-split: Wt_hi/Wt_lo transposed [N][K] bf16 ----------------
// layout in wt (shorts):
//   W0_hi @ 0      W0_lo @ 16384
//   W1_hi @ 32768  W1_lo @ 49152
//   W2_hi @ 65536  W2_lo @ 81920
//   W3_hi @ 98304  W3_lo @ 106496   (N=64)
__global__ __launch_bounds__(256) void convw_k(const float* __restrict__ W0, const float* __restrict__ W1,
                                               const float* __restrict__ W2, const float* __restrict__ W3,
                                               short* __restrict__ wt) {
    int gid = blockIdx.x * 256 + threadIdx.x;
    if (gid >= 57344) return;
    const float* W;
    int elem, Ncols, hi_base;
    if (gid < 49152) {
        int w = gid >> 14;
        elem = gid & 16383;
        Ncols = 128;
        W = (w == 0) ? W0 : (w == 1) ? W1 : W2;
        hi_base = w * 32768;
    } else {
        elem = gid - 49152;
        Ncols = 64;
        W = W3;
        hi_base = 98304;
    }
    int k = elem / Ncols, ncol = elem % Ncols;
    short hi, lo;
    split_bf16(W[elem], hi, lo);
    int dstidx = ncol * 128 + k;         // [N][K=128]
    wt[hi_base + dstidx] = hi;
    wt[hi_base + Ncols * 128 + dstidx] = lo;
}

// ---------------- MFMA GEMM: C[n x HOUT] = act(A)[n x 128] @ W ----------------
// split-bf16: acc += Ahi*Bhi + Alo*Bhi + Ahi*Blo  (lo*lo dropped, ~2^-16 rel)
// block = 256 thr = 4 waves; wave tile 16 rows x HOUT
template<int HOUT, bool RELU>
__global__ __launch_bounds__(256) void mfma_gemm_k(const float* __restrict__ A,
                                                   const short* __restrict__ wt_hi,
                                                   const short* __restrict__ wt_lo,
                                                   float* __restrict__ C, int n) {
    constexpr int NT = HOUT / 16;
    const int tid = threadIdx.x;
    const int wid = tid >> 6, lane = tid & 63;
    const int arow = blockIdx.x * 64 + wid * 16 + (lane & 15);  // A-frag row
    const int khalf = lane >> 4;                                // 0..3

    f32x4 acc[NT];
#pragma unroll
    for (int nt = 0; nt < NT; ++nt) acc[nt] = (f32x4){0.f, 0.f, 0.f, 0.f};

#pragma unroll
    for (int kc = 0; kc < 4; ++kc) {
        const int k0 = kc * 32 + khalf * 8;
        float4 a0 = make_float4(0.f, 0.f, 0.f, 0.f), a1 = a0;
        if (arow < n) {
            a0 = *(const float4*)(A + (size_t)arow * 128 + k0);
            a1 = *(const float4*)(A + (size_t)arow * 128 + k0 + 4);
        }
        if (RELU) {
            a0.x = fmaxf(a0.x, 0.f); a0.y = fmaxf(a0.y, 0.f);
            a0.z = fmaxf(a0.z, 0.f); a0.w = fmaxf(a0.w, 0.f);
            a1.x = fmaxf(a1.x, 0.f); a1.y = fmaxf(a1.y, 0.f);
            a1.z = fmaxf(a1.z, 0.f); a1.w = fmaxf(a1.w, 0.f);
        }
        frag8 ahi, alo;
        float av[8] = {a0.x, a0.y, a0.z, a0.w, a1.x, a1.y, a1.z, a1.w};
#pragma unroll
        for (int j = 0; j < 8; ++j) split_bf16(av[j], ahi.s[j], alo.s[j]);

#pragma unroll
        for (int nt = 0; nt < NT; ++nt) {
            const size_t bidx = (size_t)(nt * 16 + (lane & 15)) * 128 + k0;
            short8 bhi = *(const short8*)(wt_hi + bidx);
            short8 blo = *(const short8*)(wt_lo + bidx);
            acc[nt] = __builtin_amdgcn_mfma_f32_16x16x32_bf16(alo.v, bhi, acc[nt], 0, 0, 0);
            acc[nt] = __builtin_amdgcn_mfma_f32_16x16x32_bf16(ahi.v, blo, acc[nt], 0, 0, 0);
            acc[nt] = __builtin_amdgcn_mfma_f32_16x16x32_bf16(ahi.v, bhi, acc[nt], 0, 0, 0);
        }
    }

    // D layout: col = lane&15, row = (lane>>4)*4 + r
    const int rbase = blockIdx.x * 64 + wid * 16 + khalf * 4;
    const int col = lane & 15;
#pragma unroll
    for (int nt = 0; nt < NT; ++nt) {
#pragma unroll
        for (int r = 0; r < 4; ++r) {
            int row = rbase + r;
            if (row < n) C[(size_t)row * HOUT + nt * 16 + col] = acc[nt][r];
        }
    }
}

// ---------------- gather-aggregate (atomic-free) ----------------
template<int HOUT>
__global__ __launch_bounds__(256) void agg_k(const float* __restrict__ tmp,
                                             const int* __restrict__ csr_src,
                                             const int* __restrict__ rowptr,
                                             const float* __restrict__ dinv,
                                             const float* __restrict__ b,
                                             float* __restrict__ out, int n) {
    constexpr int LPN = HOUT / 4;
    int gid = blockIdx.x * 256 + threadIdx.x;
    int node = gid / LPN, l = gid % LPN;
    if (node >= n) return;

    const float dn = dinv[node];
    float4 bb = *(const float4*)(b + l * 4);
    float4 t = *(const float4*)(tmp + (size_t)node * HOUT + l * 4);
    float4 acc;
    acc.x = t.x * dn; acc.y = t.y * dn; acc.z = t.z * dn; acc.w = t.w * dn;

    int e = rowptr[node];
    const int end = rowptr[node + 1];
    // unroll-2: two independent gather chains
    while (e + 2 <= end) {
        int s0 = csr_src[e], s1 = csr_src[e + 1];
        float c0 = dinv[s0], c1 = dinv[s1];
        float4 v0 = *(const float4*)(tmp + (size_t)s0 * HOUT + l * 4);
        float4 v1 = *(const float4*)(tmp + (size_t)s1 * HOUT + l * 4);
        acc.x = fmaf(v0.x, c0, acc.x); acc.y = fmaf(v0.y, c0, acc.y);
        acc.z = fmaf(v0.z, c0, acc.z); acc.w = fmaf(v0.w, c0, acc.w);
        acc.x = fmaf(v1.x, c1, acc.x); acc.y = fmaf(v1.y, c1, acc.y);
        acc.z = fmaf(v1.z, c1, acc.z); acc.w = fmaf(v1.w, c1, acc.w);
        e += 2;
    }
    if (e < end) {
        int s0 = csr_src[e];
        float c0 = dinv[s0];
        float4 v0 = *(const float4*)(tmp + (size_t)s0 * HOUT + l * 4);
        acc.x = fmaf(v0.x, c0, acc.x); acc.y = fmaf(v0.y, c0, acc.y);
        acc.z = fmaf(v0.z, c0, acc.z); acc.w = fmaf(v0.w, c0, acc.w);
    }
    float4 o;
    o.x = fmaf(acc.x, dn, bb.x);
    o.y = fmaf(acc.y, dn, bb.y);
    o.z = fmaf(acc.z, dn, bb.z);
    o.w = fmaf(acc.w, dn, bb.w);
    *(float4*)(out + (size_t)node * HOUT + l * 4) = o;
}

extern "C" void kernel_launch(void* const* d_in, const int* in_sizes, int n_in,
                              void* d_out, int out_size, void* d_ws, size_t ws_size,
                              hipStream_t stream) {
    const float* x    = (const float*)d_in[0];
    const int*   ei   = (const int*)d_in[1];
    const int*   srcp = ei;
    const int*   dstp = ei + NE;
    const float* W0 = (const float*)d_in[2]; const float* b0 = (const float*)d_in[3];
    const float* W1 = (const float*)d_in[4]; const float* b1 = (const float*)d_in[5];
    const float* W2 = (const float*)d_in[6]; const float* b2 = (const float*)d_in[7];
    const float* W3 = (const float*)d_in[8]; const float* b3 = (const float*)d_in[9];
    float* out = (float*)d_out;

    char* ws = (char*)d_ws;
    size_t off = 0;
    auto alloc = [&](size_t bytes) { void* p = ws + off; off = (off + bytes + 255) & ~(size_t)255; return p; };
    int*   degi    = (int*)alloc((size_t)NN * 4);
    float* dinv    = (float*)alloc((size_t)NN * 4);
    int*   rowptr  = (int*)alloc((size_t)(NN + 1) * 4);
    int*   cursor  = (int*)alloc((size_t)NN * 4);
    int*   bsum    = (int*)alloc(64 * 4);
    int*   boff    = (int*)alloc(64 * 4);
    int*   csr_src = (int*)alloc((size_t)NE * 4);
    short* wt      = (short*)alloc((size_t)114688 * 2);
    float* bufA    = (float*)alloc((size_t)NN * 128 * 4);
    float* bufB    = (float*)alloc((size_t)NN * 128 * 4);

    const int nblk_n = (NN + 255) / 256;
    const int nblk_e = (NE + 255) / 256;
    const int nblk_scan = (NN + 4095) / 4096;   // 25
    const int nblk_g = (NN + 63) / 64;          // 1563
    const int nblk_a128 = (int)(((size_t)NN * 32 + 255) / 256);
    const int nblk_a64  = (int)(((size_t)NN * 16 + 255) / 256);

    // ---- graph preprocessing ----
    deg_init_k<<<nblk_n, 256, 0, stream>>>(degi, NN);
    deg_count_k<<<nblk_e, 256, 0, stream>>>(dstp, degi, NE);
    dinv_k<<<nblk_n, 256, 0, stream>>>(degi, dinv, NN);
    bsum_k<<<nblk_scan, 256, 0, stream>>>(degi, bsum, NN);
    bscan_k<<<1, 64, 0, stream>>>(bsum, boff, rowptr + NN, nblk_scan);
    scan2_k<<<nblk_scan, 256, 0, stream>>>(degi, boff, rowptr, cursor, NN);
    fill_k<<<nblk_e, 256, 0, stream>>>(srcp, dstp, cursor, csr_src, NE);
    convw_k<<<(57344 + 255) / 256, 256, 0, stream>>>(W0, W1, W2, W3, wt);

    const short* w0h = wt,          *w0l = wt + 16384;
    const short* w1h = wt + 32768,  *w1l = wt + 49152;
    const short* w2h = wt + 65536,  *w2l = wt + 81920;
    const short* w3h = wt + 98304,  *w3l = wt + 106496;

    // ---- layer 0 ----
    mfma_gemm_k<128, false><<<nblk_g, 256, 0, stream>>>(x, w0h, w0l, bufA, NN);
    agg_k<128><<<nblk_a128, 256, 0, stream>>>(bufA, csr_src, rowptr, dinv, b0, bufB, NN);
    // ---- layer 1 ----
    mfma_gemm_k<128, true><<<nblk_g, 256, 0, stream>>>(bufB, w1h, w1l, bufA, NN);
    agg_k<128><<<nblk_a128, 256, 0, stream>>>(bufA, csr_src, rowptr, dinv, b1, bufB, NN);
    // ---- layer 2 ----
    mfma_gemm_k<128, true><<<nblk_g, 256, 0, stream>>>(bufB, w2h, w2l, bufA, NN);
    agg_k<128><<<nblk_a128, 256, 0, stream>>>(bufA, csr_src, rowptr, dinv, b2, bufB, NN);
    // ---- layer 3 ----
    mfma_gemm_k<64, true><<<nblk_g, 256, 0, stream>>>(bufB, w3h, w3l, bufA, NN);
    agg_k<64><<<nblk_a64, 256, 0, stream>>>(bufA, csr_src, rowptr, dinv, b3, out, NN);
}